// Round 2
// baseline (2678.143 us; speedup 1.0000x reference)
//
#include <hip/hip_runtime.h>

#define T_SEQ 512
#define HID 256

typedef _Float16 half8 __attribute__((ext_vector_type(8)));
typedef _Float16 half4 __attribute__((ext_vector_type(4)));
typedef float floatx4 __attribute__((ext_vector_type(4)));

// ws layout (in f16 elements). Fragment = 64 lanes x 8 f16 = 512 elems.
// gh: [w(8)][kt(8)][nt(6)]  -> 384 frags
// gi: [w(8)][kt(2)][nt(6)]  -> 96 frags
// wb: [w(8)][kt(8)][nt(2)]  -> 128 frags
// wd: [kt(8)]               -> 8 frags
#define OFF_GH 0
#define OFF_GI (OFF_GH + 384 * 512)
#define OFF_WB (OFF_GI + 96 * 512)
#define OFF_WD (OFF_WB + 128 * 512)

__device__ __forceinline__ float sigm(float x) { return 1.0f / (1.0f + __expf(-x)); }
__device__ __forceinline__ float tanh_fast(float x) {
  float e = __expf(2.0f * x);
  return 1.0f - 2.0f / (e + 1.0f);
}

// Pack all weights (fp32 in) into f16 MFMA B-fragment order.
// B-frag for 16x16x32: lane l holds B[k=(l>>4)*8+j][n=l&15], j=0..7, where
// B = W^T, i.e. value = W[n][k..k+7] (contiguous in row-major W).
__global__ void prep_kernel(const float* __restrict__ w_ih,
                            const float* __restrict__ w_hh,
                            const float* __restrict__ w_base,
                            const float* __restrict__ w_dir,
                            const float* __restrict__ w_mag,
                            _Float16* __restrict__ ws) {
  const int f = blockIdx.x;
  const int lane = threadIdx.x;
  const int col = lane & 15, quad = lane >> 4;
  const float* src;
  int n, k, ld;
  _Float16* dst;
  if (f < 384) {  // w_hh frags: f = (w*8 + kt)*6 + nt ; nt: 0,1=r 2,3=z 4,5=n
    int nt = f % 6, kt = (f / 6) % 8, w = f / 48;
    n = (nt >> 1) * 256 + w * 32 + (nt & 1) * 16 + col;
    k = kt * 32 + quad * 8;
    src = w_hh; ld = 256;
    dst = ws + OFF_GH + f * 512 + lane * 8;
  } else if (f < 480) {  // w_ih frags: f2 = (w*2 + kt)*6 + nt
    int f2 = f - 384;
    int nt = f2 % 6, kt = (f2 / 6) % 2, w = f2 / 12;
    n = (nt >> 1) * 256 + w * 32 + (nt & 1) * 16 + col;
    k = kt * 32 + quad * 8;
    src = w_ih; ld = 64;
    dst = ws + OFF_GI + f2 * 512 + lane * 8;
  } else if (f < 608) {  // w_base frags: f3 = (w*8 + kt)*2 + nt
    int f3 = f - 480;
    int nt = f3 % 2, kt = (f3 / 2) % 8, w = f3 / 16;
    n = w * 32 + nt * 16 + col;
    k = kt * 32 + quad * 8;
    src = w_base; ld = 256;
    dst = ws + OFF_WB + f3 * 512 + lane * 8;
  } else {  // dir/mag combined into one 16-row N-tile: cols 0..7 dir, 8..15 mag
    int kt = f - 608;
    k = kt * 32 + quad * 8;
    ld = 256;
    if (col < 8) { src = w_dir; n = col; } else { src = w_mag; n = col - 8; }
    dst = ws + OFF_WD + kt * 512 + lane * 8;
  }
#pragma unroll
  for (int j = 0; j < 8; ++j)
    dst[j] = (_Float16)src[n * ld + k + j];
}

// 64 blocks x 512 threads (8 waves). Block owns 16 batch rows for all 512
// steps. h carried in fp32 REGISTERS (exact z*h path); an f16 shadow copy
// lives in LDS for the next step's MFMA A-fragments. Wave w owns gate
// columns [32w, 32w+32) of r,z,n -> h_new slice computed locally, no
// cross-wave exchange. Double-buffered x/h -> one __syncthreads per step.
// Head MLP fused at the tail.
__global__ __launch_bounds__(512, 2)
void gru_head_kernel(const float* __restrict__ x_seq,
                     const float* __restrict__ b_ih,
                     const float* __restrict__ b_hh,
                     const float* __restrict__ b_base,
                     const float* __restrict__ b_dir,
                     const float* __restrict__ b_mag,
                     const _Float16* __restrict__ ws,
                     float* __restrict__ out) {
  __shared__ __align__(16) _Float16 xbuf[2][16][72];    // 64 + 8 pad (banks)
  __shared__ __align__(16) _Float16 hbuf[2][16][264];   // 256 + 8 pad

  const int tid = threadIdx.x;
  const int lane = tid & 63;
  const int w = tid >> 6;       // wave 0..7
  const int col = lane & 15;
  const int quad = lane >> 4;
  const int row0 = blockIdx.x * 16;

  // h0 = 0 (f16 shadow)
  for (int i = tid; i < 16 * 264; i += 512)
    ((_Float16*)hbuf[0])[i] = (_Float16)0.0f;

  // stage x[0] into xbuf[0]: 256 threads x float4 (16B), fp32 -> f16
  if (tid < 256) {
    const int r = tid >> 4, seg = tid & 15;
    const float4 raw = *(const float4*)(x_seq + ((size_t)(row0 + r) * T_SEQ + 0) * 64 + seg * 4);
    half4 v;
    v[0] = (_Float16)raw.x; v[1] = (_Float16)raw.y;
    v[2] = (_Float16)raw.z; v[3] = (_Float16)raw.w;
    *(half4*)&xbuf[0][r][seg * 4] = v;
  }

  // per-wave bias registers (col-dependent only)
  float br[2], bz[2], bin_[2], bhn[2];
#pragma unroll
  for (int s = 0; s < 2; ++s) {
    const int c = w * 32 + s * 16 + col;
    br[s] = b_ih[c] + b_hh[c];
    bz[s] = b_ih[256 + c] + b_hh[256 + c];
    bin_[s] = b_ih[512 + c];
    bhn[s] = b_hh[512 + c];
  }

  // fp32 carry for the h elements this lane owns: (s, r2) -> row quad*4+r2,
  // col w*32+s*16+col — time-invariant mapping.
  float hreg[2][4];
#pragma unroll
  for (int s = 0; s < 2; ++s)
#pragma unroll
    for (int r2 = 0; r2 < 4; ++r2) hreg[s][r2] = 0.0f;

  const half8* __restrict__ ghp = (const half8*)(ws + OFF_GH) + w * (8 * 6 * 64);
  const half8* __restrict__ gip = (const half8*)(ws + OFF_GI) + w * (2 * 6 * 64);
  const half8* __restrict__ wbp = (const half8*)(ws + OFF_WB) + w * (8 * 2 * 64);
  const half8* __restrict__ wdp = (const half8*)(ws + OFF_WD);

#pragma unroll 1
  for (int t = 0; t < T_SEQ; ++t) {
    __syncthreads();
    const int cur = t & 1, nxt = cur ^ 1;

    // prefetch next x into the other buffer (no reader conflict)
    if (tid < 256 && t + 1 < T_SEQ) {
      const int r = tid >> 4, seg = tid & 15;
      const float4 raw = *(const float4*)(x_seq + ((size_t)(row0 + r) * T_SEQ + (t + 1)) * 64 + seg * 4);
      half4 v;
      v[0] = (_Float16)raw.x; v[1] = (_Float16)raw.y;
      v[2] = (_Float16)raw.z; v[3] = (_Float16)raw.w;
      *(half4*)&xbuf[nxt][r][seg * 4] = v;
    }

    // A-fragments: A[m=lane&15][k=quad*8+j] -> ds_read_b128, 2-way banks (pad)
    half8 ah[8], ax[2];
#pragma unroll
    for (int kt = 0; kt < 8; ++kt)
      ah[kt] = *(const half8*)&hbuf[cur][col][kt * 32 + quad * 8];
#pragma unroll
    for (int kt = 0; kt < 2; ++kt)
      ax[kt] = *(const half8*)&xbuf[cur][col][kt * 32 + quad * 8];

    // accs: 0,1=r  2,3=z  4,5=n_h(gh part)  6,7=n_i(gi part)
    floatx4 acc[8];
#pragma unroll
    for (int i = 0; i < 8; ++i) acc[i] = (floatx4){0.f, 0.f, 0.f, 0.f};

#pragma unroll
    for (int kt = 0; kt < 8; ++kt) {
      const half8* bp = ghp + kt * (6 * 64) + lane;
      acc[0] = __builtin_amdgcn_mfma_f32_16x16x32_f16(ah[kt], bp[0],   acc[0], 0, 0, 0);
      acc[1] = __builtin_amdgcn_mfma_f32_16x16x32_f16(ah[kt], bp[64],  acc[1], 0, 0, 0);
      acc[2] = __builtin_amdgcn_mfma_f32_16x16x32_f16(ah[kt], bp[128], acc[2], 0, 0, 0);
      acc[3] = __builtin_amdgcn_mfma_f32_16x16x32_f16(ah[kt], bp[192], acc[3], 0, 0, 0);
      acc[4] = __builtin_amdgcn_mfma_f32_16x16x32_f16(ah[kt], bp[256], acc[4], 0, 0, 0);
      acc[5] = __builtin_amdgcn_mfma_f32_16x16x32_f16(ah[kt], bp[320], acc[5], 0, 0, 0);
    }
#pragma unroll
    for (int kt = 0; kt < 2; ++kt) {
      const half8* bp = gip + kt * (6 * 64) + lane;
      acc[0] = __builtin_amdgcn_mfma_f32_16x16x32_f16(ax[kt], bp[0],   acc[0], 0, 0, 0);
      acc[1] = __builtin_amdgcn_mfma_f32_16x16x32_f16(ax[kt], bp[64],  acc[1], 0, 0, 0);
      acc[2] = __builtin_amdgcn_mfma_f32_16x16x32_f16(ax[kt], bp[128], acc[2], 0, 0, 0);
      acc[3] = __builtin_amdgcn_mfma_f32_16x16x32_f16(ax[kt], bp[192], acc[3], 0, 0, 0);
      acc[6] = __builtin_amdgcn_mfma_f32_16x16x32_f16(ax[kt], bp[256], acc[6], 0, 0, 0);
      acc[7] = __builtin_amdgcn_mfma_f32_16x16x32_f16(ax[kt], bp[320], acc[7], 0, 0, 0);
    }

    // epilogue: gates fp32; carry stays fp32 in hreg; f16 shadow -> hbuf[nxt]
    // (C-layout: row=quad*4+r2, col=lane&15)
#pragma unroll
    for (int s = 0; s < 2; ++s) {
      const int c = w * 32 + s * 16 + col;
#pragma unroll
      for (int r2 = 0; r2 < 4; ++r2) {
        const int rw = quad * 4 + r2;
        const float rr = sigm(acc[0 + s][r2] + br[s]);
        const float zz = sigm(acc[2 + s][r2] + bz[s]);
        const float nn = tanh_fast(acc[6 + s][r2] + bin_[s] + rr * (acc[4 + s][r2] + bhn[s]));
        const float hnew = zz * hreg[s][r2] + (1.0f - zz) * nn;
        hreg[s][r2] = hnew;
        hbuf[nxt][rw][c] = (_Float16)hnew;
      }
    }
  }

  __syncthreads();
  // h_T is in hbuf[0] (T=512 even). Head: base = relu(hT @ w_base^T + b_base)
  {
    floatx4 ab[2];
    ab[0] = (floatx4){0.f, 0.f, 0.f, 0.f};
    ab[1] = (floatx4){0.f, 0.f, 0.f, 0.f};
#pragma unroll
    for (int kt = 0; kt < 8; ++kt) {
      const half8 ahh = *(const half8*)&hbuf[0][col][kt * 32 + quad * 8];
      const half8* bp = wbp + kt * (2 * 64) + lane;
      ab[0] = __builtin_amdgcn_mfma_f32_16x16x32_f16(ahh, bp[0],  ab[0], 0, 0, 0);
      ab[1] = __builtin_amdgcn_mfma_f32_16x16x32_f16(ahh, bp[64], ab[1], 0, 0, 0);
    }
#pragma unroll
    for (int s = 0; s < 2; ++s) {
      const int c = w * 32 + s * 16 + col;
      const float bb = b_base[c];
#pragma unroll
      for (int r2 = 0; r2 < 4; ++r2) {
        const float v = ab[s][r2] + bb;
        hbuf[1][quad * 4 + r2][c] = (_Float16)fmaxf(v, 0.0f);
      }
    }
  }
  __syncthreads();

  // dir/mag heads: one N-tile (cols 0..7 = dir, 8..15 = mag), wave 0 only
  if (w == 0) {
    floatx4 ad = (floatx4){0.f, 0.f, 0.f, 0.f};
#pragma unroll
    for (int kt = 0; kt < 8; ++kt) {
      const half8 ahh = *(const half8*)&hbuf[1][col][kt * 32 + quad * 8];
      ad = __builtin_amdgcn_mfma_f32_16x16x32_f16(ahh, wdp[kt * 64 + lane], ad, 0, 0, 0);
    }
    const float bd = (col < 8) ? b_dir[col] : b_mag[col - 8];
#pragma unroll
    for (int r2 = 0; r2 < 4; ++r2) {
      const float v = ad[r2] + bd;
      const float act = (col < 8) ? tanh_fast(v) : sigm(v);
      const float other = __shfl_xor(act, 8, 64);
      if (col < 8)
        out[(size_t)(row0 + quad * 4 + r2) * 8 + col] = act * other;
    }
  }
}

extern "C" void kernel_launch(void* const* d_in, const int* in_sizes, int n_in,
                              void* d_out, int out_size, void* d_ws, size_t ws_size,
                              hipStream_t stream) {
  const float* x_seq  = (const float*)d_in[0];
  const float* w_ih   = (const float*)d_in[1];
  const float* w_hh   = (const float*)d_in[2];
  const float* b_ih   = (const float*)d_in[3];
  const float* b_hh   = (const float*)d_in[4];
  const float* w_base = (const float*)d_in[5];
  const float* b_base = (const float*)d_in[6];
  const float* w_dir  = (const float*)d_in[7];
  const float* b_dir  = (const float*)d_in[8];
  const float* w_mag  = (const float*)d_in[9];
  const float* b_mag  = (const float*)d_in[10];
  _Float16* ws = (_Float16*)d_ws;
  float* out = (float*)d_out;

  hipLaunchKernelGGL(prep_kernel, dim3(616), dim3(64), 0, stream,
                     w_ih, w_hh, w_base, w_dir, w_mag, ws);
  hipLaunchKernelGGL(gru_head_kernel, dim3(64), dim3(512), 0, stream,
                     x_seq, b_ih, b_hh, b_base, b_dir, b_mag, ws, out);
}

// Round 3
// 2548.885 us; speedup vs baseline: 1.0507x; 1.0507x over previous
//
#include <hip/hip_runtime.h>

#define T_SEQ 512
#define HID 256

typedef _Float16 half8 __attribute__((ext_vector_type(8)));
typedef _Float16 half4 __attribute__((ext_vector_type(4)));
typedef float floatx4 __attribute__((ext_vector_type(4)));

// ws layout (in f16 elements). Fragment = 64 lanes x 8 f16 = 512 elems.
// gh: [w(8)][kt(8)][nt(6)]  -> 384 frags
// gi: [w(8)][kt(2)][nt(6)]  -> 96 frags
// wb: [w(8)][kt(8)][nt(2)]  -> 128 frags
// wd: [kt(8)]               -> 8 frags
#define OFF_GH 0
#define OFF_GI (OFF_GH + 384 * 512)
#define OFF_WB (OFF_GI + 96 * 512)
#define OFF_WD (OFF_WB + 128 * 512)

#define MFMA16(A, B, C) __builtin_amdgcn_mfma_f32_16x16x32_f16(A, B, C, 0, 0, 0)

__device__ __forceinline__ float sigm(float x) { return 1.0f / (1.0f + __expf(-x)); }
__device__ __forceinline__ float tanh_fast(float x) {
  float e = __expf(2.0f * x);
  return 1.0f - 2.0f / (e + 1.0f);
}

// Pack all weights (fp32 in) into f16 MFMA B-fragment order.
// B-frag for 16x16x32: lane l holds B[k=(l>>4)*8+j][n=l&15], j=0..7, where
// B = W^T, i.e. value = W[n][k..k+7] (contiguous in row-major W).
__global__ void prep_kernel(const float* __restrict__ w_ih,
                            const float* __restrict__ w_hh,
                            const float* __restrict__ w_base,
                            const float* __restrict__ w_dir,
                            const float* __restrict__ w_mag,
                            _Float16* __restrict__ ws) {
  const int f = blockIdx.x;
  const int lane = threadIdx.x;
  const int col = lane & 15, quad = lane >> 4;
  const float* src;
  int n, k, ld;
  _Float16* dst;
  if (f < 384) {  // w_hh frags: f = (w*8 + kt)*6 + nt ; nt: 0,1=r 2,3=z 4,5=n
    int nt = f % 6, kt = (f / 6) % 8, w = f / 48;
    n = (nt >> 1) * 256 + w * 32 + (nt & 1) * 16 + col;
    k = kt * 32 + quad * 8;
    src = w_hh; ld = 256;
    dst = ws + OFF_GH + ((w * 8 + kt) * 6 + nt) * 512 + lane * 8;
  } else if (f < 480) {  // w_ih frags
    int f2 = f - 384;
    int nt = f2 % 6, kt = (f2 / 6) % 2, w = f2 / 12;
    n = (nt >> 1) * 256 + w * 32 + (nt & 1) * 16 + col;
    k = kt * 32 + quad * 8;
    src = w_ih; ld = 64;
    dst = ws + OFF_GI + ((w * 2 + kt) * 6 + nt) * 512 + lane * 8;
  } else if (f < 608) {  // w_base frags
    int f3 = f - 480;
    int nt = f3 % 2, kt = (f3 / 2) % 8, w = f3 / 16;
    n = w * 32 + nt * 16 + col;
    k = kt * 32 + quad * 8;
    src = w_base; ld = 256;
    dst = ws + OFF_WB + ((w * 8 + kt) * 2 + nt) * 512 + lane * 8;
  } else {  // dir/mag combined: cols 0..7 dir, 8..15 mag
    int kt = f - 608;
    k = kt * 32 + quad * 8;
    ld = 256;
    if (col < 8) { src = w_dir; n = col; } else { src = w_mag; n = col - 8; }
    dst = ws + OFF_WD + kt * 512 + lane * 8;
  }
#pragma unroll
  for (int j = 0; j < 8; ++j)
    dst[j] = (_Float16)src[n * ld + k + j];
}

// 64 blocks x 512 threads (8 waves). Block owns 16 batch rows for all 512
// steps. Weight residency per wave (60 frags): 24 in VGPRs (loaded once),
// 5 in LDS (copied once), 31 streamed from L2 per step, double-buffered in
// groups of <=8 so register-frag MFMAs cover L2 latency. h carried in fp32
// registers; f16 shadow in LDS in FRAGMENT-LINEAR layout [kt][q][row][8]
// so A-frag ds_read_b128 is base+lane*16 (conflict-free).
__global__ __launch_bounds__(512, 2)
void gru_head_kernel(const float* __restrict__ x_seq,
                     const float* __restrict__ b_ih,
                     const float* __restrict__ b_hh,
                     const float* __restrict__ b_base,
                     const float* __restrict__ b_dir,
                     const float* __restrict__ b_mag,
                     const _Float16* __restrict__ ws,
                     float* __restrict__ out) {
  __shared__ __align__(16) _Float16 hlin[2][4096];   // [kt(8)][q(4)][row(16)][8]
  __shared__ __align__(16) _Float16 xlin[2][1024];   // [kt(2)][q(4)][row(16)][8]
  __shared__ __align__(16) _Float16 wlds[8][5 * 512];

  const int tid = threadIdx.x;
  const int lane = tid & 63;
  const int w = tid >> 6;       // wave 0..7
  const int col = lane & 15;
  const int quad = lane >> 4;
  const int row0 = blockIdx.x * 16;

  // h0 = 0 (f16 shadow)
  *(half8*)&hlin[0][tid * 8] = (half8)((_Float16)0.0f);

  // stage x[0]: thread tid<256 handles (r=tid>>4, seg=tid&15) -> k0=seg*4
  if (tid < 256) {
    const int r = tid >> 4, seg = tid & 15;
    const float4 raw = *(const float4*)(x_seq + ((size_t)(row0 + r) * T_SEQ + 0) * 64 + seg * 4);
    half4 v;
    v[0] = (_Float16)raw.x; v[1] = (_Float16)raw.y;
    v[2] = (_Float16)raw.z; v[3] = (_Float16)raw.w;
    const int idx = (seg >> 3) * 512 + ((seg >> 1) & 3) * 128 + r * 8 + (seg & 1) * 4;
    *(half4*)&xlin[0][idx] = v;
  }

  // per-wave bias registers (col-dependent only)
  float br[2], bz[2], bin_[2], bhn[2];
#pragma unroll
  for (int s = 0; s < 2; ++s) {
    const int c = w * 32 + s * 16 + col;
    br[s] = b_ih[c] + b_hh[c];
    bz[s] = b_ih[256 + c] + b_hh[256 + c];
    bin_[s] = b_ih[512 + c];
    bhn[s] = b_hh[512 + c];
  }

  float hreg[2][4];
#pragma unroll
  for (int s = 0; s < 2; ++s)
#pragma unroll
    for (int r2 = 0; r2 < 4; ++r2) hreg[s][r2] = 0.0f;

  const half8* __restrict__ ghp = (const half8*)(ws + OFF_GH) + w * (48 * 64);
  const half8* __restrict__ gip = (const half8*)(ws + OFF_GI) + w * (12 * 64);
  const half8* __restrict__ wbp = (const half8*)(ws + OFF_WB) + w * (16 * 64);
  const half8* __restrict__ wdp = (const half8*)(ws + OFF_WD);

  // --- one-time residency setup ---
  // VGPR-resident: gh frags f=0..23 (kt0..3, all nt)
  half8 wreg[24];
#pragma unroll
  for (int f = 0; f < 24; ++f) wreg[f] = ghp[f * 64 + lane];
  // LDS-resident: gh frags f=24..28 (kt4, nt0..4)
  _Float16* const wlw = wlds[w];
#pragma unroll
  for (int j = 0; j < 5; ++j)
    *(half8*)&wlw[j * 512 + lane * 8] = ghp[(24 + j) * 64 + lane];
  // streamed per step: gi f0..11, gh f29..47

#pragma unroll 1
  for (int t = 0; t < T_SEQ; ++t) {
    __syncthreads();
    const int cur = t & 1, nxt = cur ^ 1;

    // prefetch next x into the other buffer
    if (tid < 256 && t + 1 < T_SEQ) {
      const int r = tid >> 4, seg = tid & 15;
      const float4 raw = *(const float4*)(x_seq + ((size_t)(row0 + r) * T_SEQ + (t + 1)) * 64 + seg * 4);
      half4 v;
      v[0] = (_Float16)raw.x; v[1] = (_Float16)raw.y;
      v[2] = (_Float16)raw.z; v[3] = (_Float16)raw.w;
      const int idx = (seg >> 3) * 512 + ((seg >> 1) & 3) * 128 + r * 8 + (seg & 1) * 4;
      *(half4*)&xlin[nxt][idx] = v;
    }

    // A-fragments: perfectly linear ds_read_b128 (base + lane*16)
    half8 ah[8], ax0, ax1;
#pragma unroll
    for (int kt = 0; kt < 8; ++kt)
      ah[kt] = *(const half8*)&hlin[cur][kt * 512 + lane * 8];
    ax0 = *(const half8*)&xlin[cur][lane * 8];
    ax1 = *(const half8*)&xlin[cur][512 + lane * 8];

    // accs: 0,1=r  2,3=z  4,5=n_h  6,7=n_i
    floatx4 acc[8];
#pragma unroll
    for (int i = 0; i < 8; ++i) acc[i] = (floatx4){0.f, 0.f, 0.f, 0.f};

    // issue stream group 1: gi f0..7
    half8 sf[8];
#pragma unroll
    for (int i = 0; i < 8; ++i) sf[i] = gip[i * 64 + lane];

    // Phase A: 24 register-frag MFMAs (covers group-1 latency)
#pragma unroll
    for (int f = 0; f < 24; ++f)
      acc[f % 6] = MFMA16(ah[f / 6], wreg[f], acc[f % 6]);

    // issue group 2: gi f8..11 + gh f29..32
    half8 sg[8];
#pragma unroll
    for (int i = 0; i < 4; ++i) sg[i] = gip[(8 + i) * 64 + lane];
#pragma unroll
    for (int i = 0; i < 4; ++i) sg[4 + i] = ghp[(29 + i) * 64 + lane];

    // Phase B: consume group 1 (gi f0..7; kt = f/6, nt = f%6)
#pragma unroll
    for (int i = 0; i < 8; ++i) {
      const int nt = (i < 6) ? i : (i - 6);
      const int aidx = (nt < 4) ? nt : nt + 2;
      acc[aidx] = MFMA16((i < 6) ? ax0 : ax1, sf[i], acc[aidx]);
    }

    // issue group 3: gh f33..40
    half8 sh[8];
#pragma unroll
    for (int i = 0; i < 8; ++i) sh[i] = ghp[(33 + i) * 64 + lane];

    // Phase C: consume group 2 (gi f8..11: kt1 nt2..5; gh f29..32)
#pragma unroll
    for (int i = 0; i < 4; ++i) {
      const int nt = 2 + i;
      const int aidx = (nt < 4) ? nt : nt + 2;
      acc[aidx] = MFMA16(ax1, sg[i], acc[aidx]);
    }
#pragma unroll
    for (int i = 0; i < 4; ++i) {
      const int f = 29 + i, kt = f / 6, nt = f % 6;
      acc[nt] = MFMA16(ah[kt], sg[4 + i], acc[nt]);
    }

    // issue group 4: gh f41..47
    half8 st[7];
#pragma unroll
    for (int i = 0; i < 7; ++i) st[i] = ghp[(41 + i) * 64 + lane];

    // Phase D: consume group 3 (gh f33..40)
#pragma unroll
    for (int i = 0; i < 8; ++i) {
      const int f = 33 + i, kt = f / 6, nt = f % 6;
      acc[nt] = MFMA16(ah[kt], sh[i], acc[nt]);
    }

    // Phase E: LDS-resident frags (gh f24..28 = kt4 nt0..4) + group 4
#pragma unroll
    for (int j = 0; j < 5; ++j) {
      const half8 wb_ = *(const half8*)&wlw[j * 512 + lane * 8];
      acc[j] = MFMA16(ah[4], wb_, acc[j]);
    }
#pragma unroll
    for (int i = 0; i < 7; ++i) {
      const int f = 41 + i, kt = f / 6, nt = f % 6;
      acc[nt] = MFMA16(ah[kt], st[i], acc[nt]);
    }

    // epilogue: gates fp32; carry in hreg; f16 shadow -> hlin[nxt]
    // write index: c = w*32+s*16+col -> [kt=w][q=(s*16+col)>>3][row][c&7]
#pragma unroll
    for (int s = 0; s < 2; ++s) {
      const int inner = s * 16 + col;
      const int widx = w * 512 + (inner >> 3) * 128 + (col & 7);
#pragma unroll
      for (int r2 = 0; r2 < 4; ++r2) {
        const int rw = quad * 4 + r2;
        const float rr = sigm(acc[0 + s][r2] + br[s]);
        const float zz = sigm(acc[2 + s][r2] + bz[s]);
        const float nn = tanh_fast(acc[6 + s][r2] + bin_[s] + rr * (acc[4 + s][r2] + bhn[s]));
        const float hnew = zz * hreg[s][r2] + (1.0f - zz) * nn;
        hreg[s][r2] = hnew;
        hlin[nxt][widx + rw * 8] = (_Float16)hnew;
      }
    }
  }

  __syncthreads();
  // h_T is in hlin[0] (T=512 even). base = relu(hT @ w_base^T + b_base)
  {
    floatx4 ab[2];
    ab[0] = (floatx4){0.f, 0.f, 0.f, 0.f};
    ab[1] = (floatx4){0.f, 0.f, 0.f, 0.f};
#pragma unroll
    for (int kt = 0; kt < 8; ++kt) {
      const half8 ahh = *(const half8*)&hlin[0][kt * 512 + lane * 8];
      const half8* bp = wbp + kt * (2 * 64) + lane;
      ab[0] = MFMA16(ahh, bp[0],  ab[0]);
      ab[1] = MFMA16(ahh, bp[64], ab[1]);
    }
#pragma unroll
    for (int s = 0; s < 2; ++s) {
      const int inner = s * 16 + col;
      const int widx = w * 512 + (inner >> 3) * 128 + (col & 7);
      const float bb = b_base[w * 32 + inner];
#pragma unroll
      for (int r2 = 0; r2 < 4; ++r2) {
        const float v = ab[s][r2] + bb;
        hlin[1][widx + (quad * 4 + r2) * 8] = (_Float16)fmaxf(v, 0.0f);
      }
    }
  }
  __syncthreads();

  // dir/mag heads: one N-tile (cols 0..7 = dir, 8..15 = mag), wave 0 only
  if (w == 0) {
    floatx4 ad = (floatx4){0.f, 0.f, 0.f, 0.f};
#pragma unroll
    for (int kt = 0; kt < 8; ++kt) {
      const half8 ahh = *(const half8*)&hlin[1][kt * 512 + lane * 8];
      ad = MFMA16(ahh, wdp[kt * 64 + lane], ad);
    }
    const float bd = (col < 8) ? b_dir[col] : b_mag[col - 8];
#pragma unroll
    for (int r2 = 0; r2 < 4; ++r2) {
      const float v = ad[r2] + bd;
      const float act = (col < 8) ? tanh_fast(v) : sigm(v);
      const float other = __shfl_xor(act, 8, 64);
      if (col < 8)
        out[(size_t)(row0 + quad * 4 + r2) * 8 + col] = act * other;
    }
  }
}

extern "C" void kernel_launch(void* const* d_in, const int* in_sizes, int n_in,
                              void* d_out, int out_size, void* d_ws, size_t ws_size,
                              hipStream_t stream) {
  const float* x_seq  = (const float*)d_in[0];
  const float* w_ih   = (const float*)d_in[1];
  const float* w_hh   = (const float*)d_in[2];
  const float* b_ih   = (const float*)d_in[3];
  const float* b_hh   = (const float*)d_in[4];
  const float* w_base = (const float*)d_in[5];
  const float* b_base = (const float*)d_in[6];
  const float* w_dir  = (const float*)d_in[7];
  const float* b_dir  = (const float*)d_in[8];
  const float* w_mag  = (const float*)d_in[9];
  const float* b_mag  = (const float*)d_in[10];
  _Float16* ws = (_Float16*)d_ws;
  float* out = (float*)d_out;

  hipLaunchKernelGGL(prep_kernel, dim3(616), dim3(64), 0, stream,
                     w_ih, w_hh, w_base, w_dir, w_mag, ws);
  hipLaunchKernelGGL(gru_head_kernel, dim3(64), dim3(512), 0, stream,
                     x_seq, b_ih, b_hh, b_base, b_dir, b_mag, ws, out);
}

// Round 4
// 2187.437 us; speedup vs baseline: 1.2243x; 1.1652x over previous
//
#include <hip/hip_runtime.h>

#define T_SEQ 512
#define HID 256

typedef _Float16 half8 __attribute__((ext_vector_type(8)));
typedef _Float16 half4 __attribute__((ext_vector_type(4)));
typedef float floatx4 __attribute__((ext_vector_type(4)));

// ws layout (in f16 elements). Fragment = 64 lanes x 8 f16 = 512 elems.
// gh: [w(8)][kt(8)][nt(6)]  -> 384 frags
// gi: [w(8)][kt(2)][nt(6)]  -> 96 frags
// wb: [w(8)][kt(8)][nt(2)]  -> 128 frags
// wd: [kt(8)]               -> 8 frags
#define OFF_GH 0
#define OFF_GI (OFF_GH + 384 * 512)
#define OFF_WB (OFF_GI + 96 * 512)
#define OFF_WD (OFF_WB + 128 * 512)

#define MFMA16(A, B, C) __builtin_amdgcn_mfma_f32_16x16x32_f16(A, B, C, 0, 0, 0)

__device__ __forceinline__ float sigm(float x) { return 1.0f / (1.0f + __expf(-x)); }
__device__ __forceinline__ float tanh_fast(float x) {
  float e = __expf(2.0f * x);
  return 1.0f - 2.0f / (e + 1.0f);
}

// Pack all weights (fp32 in) into f16 MFMA B-fragment order.
// B-frag for 16x16x32: lane l holds B[k=(l>>4)*8+j][n=l&15], j=0..7, where
// B = W^T, i.e. value = W[n][k..k+7] (contiguous in row-major W).
__global__ void prep_kernel(const float* __restrict__ w_ih,
                            const float* __restrict__ w_hh,
                            const float* __restrict__ w_base,
                            const float* __restrict__ w_dir,
                            const float* __restrict__ w_mag,
                            _Float16* __restrict__ ws) {
  const int f = blockIdx.x;
  const int lane = threadIdx.x;
  const int col = lane & 15, quad = lane >> 4;
  const float* src;
  int n, k, ld;
  _Float16* dst;
  if (f < 384) {  // w_hh frags: f = (w*8 + kt)*6 + nt ; nt: 0,1=r 2,3=z 4,5=n
    int nt = f % 6, kt = (f / 6) % 8, w = f / 48;
    n = (nt >> 1) * 256 + w * 32 + (nt & 1) * 16 + col;
    k = kt * 32 + quad * 8;
    src = w_hh; ld = 256;
    dst = ws + OFF_GH + ((w * 8 + kt) * 6 + nt) * 512 + lane * 8;
  } else if (f < 480) {  // w_ih frags
    int f2 = f - 384;
    int nt = f2 % 6, kt = (f2 / 6) % 2, w = f2 / 12;
    n = (nt >> 1) * 256 + w * 32 + (nt & 1) * 16 + col;
    k = kt * 32 + quad * 8;
    src = w_ih; ld = 64;
    dst = ws + OFF_GI + ((w * 2 + kt) * 6 + nt) * 512 + lane * 8;
  } else if (f < 608) {  // w_base frags
    int f3 = f - 480;
    int nt = f3 % 2, kt = (f3 / 2) % 8, w = f3 / 16;
    n = w * 32 + nt * 16 + col;
    k = kt * 32 + quad * 8;
    src = w_base; ld = 256;
    dst = ws + OFF_WB + ((w * 8 + kt) * 2 + nt) * 512 + lane * 8;
  } else {  // dir/mag combined: cols 0..7 dir, 8..15 mag
    int kt = f - 608;
    k = kt * 32 + quad * 8;
    ld = 256;
    if (col < 8) { src = w_dir; n = col; } else { src = w_mag; n = col - 8; }
    dst = ws + OFF_WD + kt * 512 + lane * 8;
  }
#pragma unroll
  for (int j = 0; j < 8; ++j)
    dst[j] = (_Float16)src[n * ld + k + j];
}

// 64 blocks x 512 threads (8 waves). Block owns 16 batch rows for all 512
// steps. Residency per wave (60 frags): 16 in VGPR/AGPR (wreg), 8 in LDS
// (wlds), 36 streamed from L2 per step in 6-frag batches issued right after
// the barrier and consumed two batches later (latency covered by MFMA).
// x comes in via per-lane register prefetch (the exact A-frag elements),
// one full step ahead -> no LDS round trip, no head vmcnt stall, and
// nothing in flight when __syncthreads drains vmcnt. h carried in fp32
// registers; f16 shadow in LDS fragment-linear [kt][q][row][8].
__global__ __launch_bounds__(512, 2)
void gru_head_kernel(const float* __restrict__ x_seq,
                     const float* __restrict__ b_ih,
                     const float* __restrict__ b_hh,
                     const float* __restrict__ b_base,
                     const float* __restrict__ b_dir,
                     const float* __restrict__ b_mag,
                     const _Float16* __restrict__ ws,
                     float* __restrict__ out) {
  __shared__ __align__(16) _Float16 hlin[2][4096];   // [kt(8)][q(4)][row(16)][8]
  __shared__ __align__(16) _Float16 wlds[8][4096];   // 8 frags per wave

  const int tid = threadIdx.x;
  const int lane = tid & 63;
  const int w = tid >> 6;       // wave 0..7
  const int col = lane & 15;
  const int quad = lane >> 4;
  const int row0 = blockIdx.x * 16;

  // h0 = 0 (f16 shadow)
  *(half8*)&hlin[0][tid * 8] = (half8)((_Float16)0.0f);

  // per-wave bias registers (col-dependent only)
  float br[2], bz[2], bin_[2], bhn[2];
#pragma unroll
  for (int s = 0; s < 2; ++s) {
    const int c = w * 32 + s * 16 + col;
    br[s] = b_ih[c] + b_hh[c];
    bz[s] = b_ih[256 + c] + b_hh[256 + c];
    bin_[s] = b_ih[512 + c];
    bhn[s] = b_hh[512 + c];
  }

  float hreg[2][4];
#pragma unroll
  for (int s = 0; s < 2; ++s)
#pragma unroll
    for (int r2 = 0; r2 < 4; ++r2) hreg[s][r2] = 0.0f;

  const half8* __restrict__ ghp = (const half8*)(ws + OFF_GH) + w * (48 * 64);
  const half8* __restrict__ gip = (const half8*)(ws + OFF_GI) + w * (12 * 64);
  const half8* __restrict__ wbp = (const half8*)(ws + OFF_WB) + w * (16 * 64);
  const half8* __restrict__ wdp = (const half8*)(ws + OFF_WD);

  // --- one-time residency setup ---
  // VGPR/AGPR-resident: gh frags f=0..15 (kt0,1 all nt; kt2 nt0..3)
  half8 wreg[16];
#pragma unroll
  for (int f = 0; f < 16; ++f) wreg[f] = ghp[f * 64 + lane];
  // LDS-resident: gh frags f=16..23 (kt2 nt4,5; kt3 nt0..5)
  _Float16* const wlw = wlds[w];
#pragma unroll
  for (int j = 0; j < 8; ++j)
    *(half8*)&wlw[j * 512 + lane * 8] = ghp[(16 + j) * 64 + lane];
  // streamed per step: gh f24..47 (kt4..7), gi f0..11

  // per-lane x pointer: A[m=col][k=quad*8+j]; x_seq row-major [B][T][64]
  const float* const xlane = x_seq + ((size_t)(row0 + col) * T_SEQ) * 64 + quad * 8;

  // x double register set: [0..1]=kt0 (k quad*8..+7), [2..3]=kt1 (+32)
  float4 xc[4], xn[4];
  {
    const float* p = xlane;  // t = 0
    xc[0] = *(const float4*)(p);
    xc[1] = *(const float4*)(p + 4);
    xc[2] = *(const float4*)(p + 32);
    xc[3] = *(const float4*)(p + 36);
  }

  auto body = [&](int t, int tpre, int cur, float4* xcur, float4* xnext) {
    const int nxt = cur ^ 1;
    __syncthreads();

    // ---- issue phase (nothing outstanding at the barrier above) ----
    // stream batches S1,S2: gh f24..29, f30..35
    half8 s1[6], s2[6];
#pragma unroll
    for (int i = 0; i < 6; ++i) s1[i] = ghp[(24 + i) * 64 + lane];
#pragma unroll
    for (int i = 0; i < 6; ++i) s2[i] = ghp[(30 + i) * 64 + lane];
    // x prefetch for tpre (consumed next body; drained by next barrier)
    {
      const float* p = xlane + (size_t)tpre * 64;
      xnext[0] = *(const float4*)(p);
      xnext[1] = *(const float4*)(p + 4);
      xnext[2] = *(const float4*)(p + 32);
      xnext[3] = *(const float4*)(p + 36);
    }

    // A-fragments from LDS: linear ds_read_b128
    half8 ah[8];
#pragma unroll
    for (int kt = 0; kt < 8; ++kt)
      ah[kt] = *(const half8*)&hlin[cur][kt * 512 + lane * 8];
    half8 wl[8];
#pragma unroll
    for (int j = 0; j < 8; ++j)
      wl[j] = *(const half8*)&wlw[j * 512 + lane * 8];

    // cvt current x -> f16 A-frags
    half8 ax0, ax1;
#pragma unroll
    for (int j = 0; j < 4; ++j) {
      ax0[j]     = (_Float16)((const float*)&xcur[0])[j];
      ax0[4 + j] = (_Float16)((const float*)&xcur[1])[j];
      ax1[j]     = (_Float16)((const float*)&xcur[2])[j];
      ax1[4 + j] = (_Float16)((const float*)&xcur[3])[j];
    }

    // accs: 0,1=r  2,3=z  4,5=n_h  6,7=n_i
    floatx4 acc[8];
#pragma unroll
    for (int i = 0; i < 8; ++i) acc[i] = (floatx4){0.f, 0.f, 0.f, 0.f};

    // Phase A: 16 register-resident MFMAs (covers S1/S2 latency)
#pragma unroll
    for (int f = 0; f < 16; ++f)
      acc[f % 6] = MFMA16(ah[f / 6], wreg[f], acc[f % 6]);

    // issue S3: gh f36..41
    half8 s3[6];
#pragma unroll
    for (int i = 0; i < 6; ++i) s3[i] = ghp[(36 + i) * 64 + lane];

    // Phase B: LDS-resident frags f16..23
#pragma unroll
    for (int j = 0; j < 8; ++j) {
      const int f = 16 + j;
      acc[f % 6] = MFMA16(ah[f / 6], wl[j], acc[f % 6]);
    }

    // Phase C: consume S1 (f24..29)
#pragma unroll
    for (int i = 0; i < 6; ++i) {
      const int f = 24 + i;
      acc[f % 6] = MFMA16(ah[f / 6], s1[i], acc[f % 6]);
    }

    // issue S4: gh f42..47
    half8 s4[6];
#pragma unroll
    for (int i = 0; i < 6; ++i) s4[i] = ghp[(42 + i) * 64 + lane];

    // Phase D: consume S2 (f30..35)
#pragma unroll
    for (int i = 0; i < 6; ++i) {
      const int f = 30 + i;
      acc[f % 6] = MFMA16(ah[f / 6], s2[i], acc[f % 6]);
    }

    // issue S5: gi f0..5 (kt0)
    half8 s5[6];
#pragma unroll
    for (int i = 0; i < 6; ++i) s5[i] = gip[i * 64 + lane];

    // Phase E: consume S3 (f36..41)
#pragma unroll
    for (int i = 0; i < 6; ++i) {
      const int f = 36 + i;
      acc[f % 6] = MFMA16(ah[f / 6], s3[i], acc[f % 6]);
    }

    // issue S6: gi f6..11 (kt1)
    half8 s6[6];
#pragma unroll
    for (int i = 0; i < 6; ++i) s6[i] = gip[(6 + i) * 64 + lane];

    // Phase F: consume S4 (f42..47)
#pragma unroll
    for (int i = 0; i < 6; ++i) {
      const int f = 42 + i;
      acc[f % 6] = MFMA16(ah[f / 6], s4[i], acc[f % 6]);
    }

    // Phase G: consume S5 (gi kt0: nt0..5 -> acc 0..3, 6,7 pattern)
#pragma unroll
    for (int i = 0; i < 6; ++i) {
      const int aidx = (i < 4) ? i : i + 2;
      acc[aidx] = MFMA16(ax0, s5[i], acc[aidx]);
    }
    // Phase H: consume S6 (gi kt1)
#pragma unroll
    for (int i = 0; i < 6; ++i) {
      const int aidx = (i < 4) ? i : i + 2;
      acc[aidx] = MFMA16(ax1, s6[i], acc[aidx]);
    }

    // epilogue: gates fp32; carry in hreg; f16 shadow -> hlin[nxt]
#pragma unroll
    for (int s = 0; s < 2; ++s) {
      const int inner = s * 16 + col;
      const int widx = w * 512 + (inner >> 3) * 128 + (col & 7);
#pragma unroll
      for (int r2 = 0; r2 < 4; ++r2) {
        const int rw = quad * 4 + r2;
        const float rr = sigm(acc[0 + s][r2] + br[s]);
        const float zz = sigm(acc[2 + s][r2] + bz[s]);
        const float nn = tanh_fast(acc[6 + s][r2] + bin_[s] + rr * (acc[4 + s][r2] + bhn[s]));
        const float hnew = zz * hreg[s][r2] + (1.0f - zz) * nn;
        hreg[s][r2] = hnew;
        hlin[nxt][widx + rw * 8] = (_Float16)hnew;
      }
    }
  };

#pragma unroll 1
  for (int t = 0; t < T_SEQ; t += 2) {
    body(t, t + 1, 0, xc, xn);
    const int tp2 = (t + 2 < T_SEQ) ? (t + 2) : (T_SEQ - 1);
    body(t + 1, tp2, 1, xn, xc);
  }

  __syncthreads();
  // h_T is in hlin[0] (T=512 even). base = relu(hT @ w_base^T + b_base)
  {
    floatx4 ab[2];
    ab[0] = (floatx4){0.f, 0.f, 0.f, 0.f};
    ab[1] = (floatx4){0.f, 0.f, 0.f, 0.f};
#pragma unroll
    for (int kt = 0; kt < 8; ++kt) {
      const half8 ahh = *(const half8*)&hlin[0][kt * 512 + lane * 8];
      const half8* bp = wbp + kt * (2 * 64) + lane;
      ab[0] = MFMA16(ahh, bp[0],  ab[0]);
      ab[1] = MFMA16(ahh, bp[64], ab[1]);
    }
#pragma unroll
    for (int s = 0; s < 2; ++s) {
      const int inner = s * 16 + col;
      const int widx = w * 512 + (inner >> 3) * 128 + (col & 7);
      const float bb = b_base[w * 32 + inner];
#pragma unroll
      for (int r2 = 0; r2 < 4; ++r2) {
        const float v = ab[s][r2] + bb;
        hlin[1][widx + (quad * 4 + r2) * 8] = (_Float16)fmaxf(v, 0.0f);
      }
    }
  }
  __syncthreads();

  // dir/mag heads: one N-tile (cols 0..7 = dir, 8..15 = mag), wave 0 only
  if (w == 0) {
    floatx4 ad = (floatx4){0.f, 0.f, 0.f, 0.f};
#pragma unroll
    for (int kt = 0; kt < 8; ++kt) {
      const half8 ahh = *(const half8*)&hlin[1][kt * 512 + lane * 8];
      ad = MFMA16(ahh, wdp[kt * 64 + lane], ad);
    }
    const float bd = (col < 8) ? b_dir[col] : b_mag[col - 8];
#pragma unroll
    for (int r2 = 0; r2 < 4; ++r2) {
      const float v = ad[r2] + bd;
      const float act = (col < 8) ? tanh_fast(v) : sigm(v);
      const float other = __shfl_xor(act, 8, 64);
      if (col < 8)
        out[(size_t)(row0 + quad * 4 + r2) * 8 + col] = act * other;
    }
  }
}

extern "C" void kernel_launch(void* const* d_in, const int* in_sizes, int n_in,
                              void* d_out, int out_size, void* d_ws, size_t ws_size,
                              hipStream_t stream) {
  const float* x_seq  = (const float*)d_in[0];
  const float* w_ih   = (const float*)d_in[1];
  const float* w_hh   = (const float*)d_in[2];
  const float* b_ih   = (const float*)d_in[3];
  const float* b_hh   = (const float*)d_in[4];
  const float* w_base = (const float*)d_in[5];
  const float* b_base = (const float*)d_in[6];
  const float* w_dir  = (const float*)d_in[7];
  const float* b_dir  = (const float*)d_in[8];
  const float* w_mag  = (const float*)d_in[9];
  const float* b_mag  = (const float*)d_in[10];
  _Float16* ws = (_Float16*)d_ws;
  float* out = (float*)d_out;

  hipLaunchKernelGGL(prep_kernel, dim3(616), dim3(64), 0, stream,
                     w_ih, w_hh, w_base, w_dir, w_mag, ws);
  hipLaunchKernelGGL(gru_head_kernel, dim3(64), dim3(512), 0, stream,
                     x_seq, b_ih, b_hh, b_base, b_dir, b_mag, ws, out);
}